// Round 11
// baseline (195.776 us; speedup 1.0000x reference)
//
#include <hip/hip_runtime.h>

#define NB 128
#define NP 576
#define NK 9
#define EMB 768
#define SGRID 24
#define COMPF 3.0f
#define NITER 10
#define EPSV 1e-8f
#define CSTR 772   // per-cluster stride in pcent: 768 ch + sx,sy,w,pad

typedef short v8s __attribute__((ext_vector_type(8)));
typedef float v4f __attribute__((ext_vector_type(4)));

__device__ __forceinline__ unsigned short f2b(float f) {
    unsigned x = __float_as_uint(f);
    unsigned r = (x + 0x7fffu + ((x >> 16) & 1u)) >> 16;
    return (unsigned short)r;
}
__device__ __forceinline__ float b2f(unsigned short u) {
    return __uint_as_float(((unsigned)u) << 16);
}

// async global->LDS, 16B per lane: dest = wave-uniform base + lane*16
__device__ __forceinline__ void gload16(const unsigned short* g, unsigned short* l) {
    __builtin_amdgcn_global_load_lds(
        (const __attribute__((address_space(1))) unsigned int*)g,
        (__attribute__((address_space(3))) unsigned int*)l, 16, 0, 0);
}

// ---------------- init: fp32->bf16 conversion + indicator partials ----------
// unchanged (proven ~58us, near HBM floor). 9 tiles of 64 points per item.
__global__ __launch_bounds__(192) void init_k(const float* __restrict__ emb,
                                              unsigned short* __restrict__ embb,
                                              float* __restrict__ pcent,
                                              int* __restrict__ chgflag) {
    int blk = blockIdx.x, b = blk / 9, pb = blk % 9;
    int t = threadIdx.x;
    int ay = pb / 3;

    if (pb == 0 && t == 0) chgflag[b] = 0;

    float a0x=0,a0y=0,a0z=0,a0w=0, a1x=0,a1y=0,a1z=0,a1w=0, a2x=0,a2y=0,a2z=0,a2w=0;
    const float* eg = emb + ((size_t)b * NP + pb * 64) * EMB + t * 4;
    unsigned short* og = embb + ((size_t)b * NP + pb * 64) * EMB + t * 4;
    for (int p = 0; p < 64; ++p) {
        float4 f = *(const float4*)(eg + (size_t)p * EMB);
        ushort4 u;
        u.x = f2b(f.x); u.y = f2b(f.y); u.z = f2b(f.z); u.w = f2b(f.w);
        *(ushort4*)(og + (size_t)p * EMB) = u;
        int pg = pb * 64 + p;
        int sel = (pg % SGRID) >> 3;
        bool m0 = (sel == 0), m1 = (sel == 1), m2 = (sel == 2);
        a0x += m0 ? f.x : 0.f; a0y += m0 ? f.y : 0.f; a0z += m0 ? f.z : 0.f; a0w += m0 ? f.w : 0.f;
        a1x += m1 ? f.x : 0.f; a1y += m1 ? f.y : 0.f; a1z += m1 ? f.z : 0.f; a1w += m1 ? f.w : 0.f;
        a2x += m2 ? f.x : 0.f; a2y += m2 ? f.y : 0.f; a2z += m2 ? f.z : 0.f; a2w += m2 ? f.w : 0.f;
    }
    float* pc = pcent + (size_t)(b * 9 + pb) * NK * CSTR;
    #pragma unroll
    for (int k = 0; k < NK; ++k) {
        int s = k - ay * 3;
        float4 v = make_float4(0.f, 0.f, 0.f, 0.f);
        if (s == 0) v = make_float4(a0x, a0y, a0z, a0w);
        if (s == 1) v = make_float4(a1x, a1y, a1z, a1w);
        if (s == 2) v = make_float4(a2x, a2y, a2z, a2w);
        *(float4*)&pc[k * CSTR + t * 4] = v;
    }
    if (t < NK) {
        int s = t - ay * 3;
        float w = 0.f, sx = 0.f, sy = 0.f;
        if (s >= 0 && s < 3) {
            for (int p = 0; p < 64; ++p) {
                int pg = pb * 64 + p;
                if (((pg % SGRID) >> 3) == s) {
                    w += 1.f;
                    sx += (float)(pg % SGRID) * COMPF;
                    sy += (float)(pg / SGRID) * COMPF;
                }
            }
        }
        pc[t * CSTR + 768] = sx; pc[t * CSTR + 769] = sy; pc[t * CSTR + 770] = w;
    }
}

// ---------------- fused: barrier-free MFMA assign + WTA partial update ------
// grid NB*6, 384 thr (6 waves), 96-point tiles. Wave-private A staging via
// global_load_lds 3-slot ring + counted vmcnt(2). B zero-row aliased (10 rows).
// ~53.6KB LDS -> 3 blocks/CU = 18 waves/CU. Partials land in slots 0..5 of the
// item's 9-slot pcent region (9-tile item stride — shared with init_k).
__global__ __launch_bounds__(384) void fused_k(
    const unsigned short* __restrict__ embb,
    const unsigned short* __restrict__ centb,
    const float* __restrict__ csp,
    float* __restrict__ pcent,
    unsigned char* __restrict__ prev,
    int* __restrict__ chgflag,
    int itFirst,              // 1: A_0 pass (no out); 0: compare + softmax out
    float* __restrict__ out)
{
    __shared__ unsigned short sc[10][776];                  // 9 clusters + zero row
    __shared__ __align__(16) unsigned short sa[6][3][16][64]; // [wave][slot][row][ch]
    __shared__ float scx[16], scy[16], sc2[16];
    __shared__ unsigned char swin[96];
    __shared__ int scnt[NK];
    __shared__ unsigned char splist[NK][96];
    __shared__ int tileChg;

    int blk = blockIdx.x;
    int b = blk / 6, pb = blk % 6;
    int t = threadIdx.x, lane = t & 63, wv = t / 64;
    int r16 = lane & 15, g = lane >> 4;

    // stage 9 centroids (B) + one zero row (aliased for clusters 9..15)
    const unsigned short* cg = centb + (size_t)b * NK * EMB;
    for (int i = t; i < NK * 96; i += 384) {
        int k = i / 96, s = i % 96;
        *(v8s*)&sc[k][s * 8] = *(const v8s*)&cg[k * EMB + s * 8];
    }
    for (int i = t; i < 96; i += 384) {
        v8s z = {0,0,0,0,0,0,0,0};
        *(v8s*)&sc[NK][i * 8] = z;
    }
    if (t < 16) {
        scx[t] = (t < NK) ? csp[((size_t)b * NK + t) * 2 + 0] : 0.f;
        scy[t] = (t < NK) ? csp[((size_t)b * NK + t) * 2 + 1] : 0.f;
    }
    if (t == 0) tileChg = itFirst;

    // per-lane pre-swizzled global source: lane l stages
    // (row = wv*16 + j*8 + (l>>3), phys slice l&7) <- logical slice (l&7)^(l>>3)
    const unsigned short* eg = embb + ((size_t)b * NP + pb * 96) * EMB;
    const unsigned short* gb = eg + (size_t)(wv * 16 + (lane >> 3)) * EMB
                                  + (size_t)(((lane & 7) ^ (lane >> 3)) * 8);

    // prologue: chunks 0,1 into slots 0,1
    gload16(gb,                 &sa[wv][0][0][0]);
    gload16(gb + 8 * EMB,       &sa[wv][0][8][0]);
    gload16(gb + 64,            &sa[wv][1][0][0]);
    gload16(gb + 8 * EMB + 64,  &sa[wv][1][8][0]);

    __syncthreads();   // sc/scx/scy staged

    // c2: wave wv handles clusters wv, wv+6
    for (int k = wv; k < NK; k += 6) {
        float s = 0.f;
        const unsigned short* ck = sc[k];
        #pragma unroll
        for (int c = 0; c < 12; ++c) { float v = b2f(ck[lane + c * 64]); s += v * v; }
        #pragma unroll
        for (int m = 1; m < 64; m <<= 1) s += __shfl_xor(s, m);
        if (lane == 0) sc2[k] = s + scx[k] * scx[k] + scy[k] * scy[k];
    }
    if (t >= NK && t < 16) sc2[t] = 1e30f;

    // K-loop: 12 chunks of 64ch, wave-private, zero barriers
    v4f acc = {0.f, 0.f, 0.f, 0.f};
    const unsigned short* scrow = sc[(r16 < NK) ? r16 : NK];
    int xk = r16 & 7;

    #pragma unroll
    for (int cn = 0; cn < 11; ++cn) {
        __builtin_amdgcn_sched_barrier(0);
        asm volatile("s_waitcnt vmcnt(2)" ::: "memory");   // chunk cn staged
        __builtin_amdgcn_sched_barrier(0);
        if (cn < 10) {
            int sl = (cn + 2) % 3;
            gload16(gb + (cn + 2) * 64,           &sa[wv][sl][0][0]);
            gload16(gb + 8 * EMB + (cn + 2) * 64, &sa[wv][sl][8][0]);
        }
        int cur = cn % 3;
        v8s a0 = *(const v8s*)&sa[wv][cur][r16][((g) ^ xk) * 8];
        v8s b0 = *(const v8s*)&scrow[cn * 64 + g * 8];
        acc = __builtin_amdgcn_mfma_f32_16x16x32_bf16(a0, b0, acc, 0, 0, 0);
        v8s a1 = *(const v8s*)&sa[wv][cur][r16][((4 + g) ^ xk) * 8];
        v8s b1 = *(const v8s*)&scrow[cn * 64 + 32 + g * 8];
        acc = __builtin_amdgcn_mfma_f32_16x16x32_bf16(a1, b1, acc, 0, 0, 0);
    }
    __builtin_amdgcn_sched_barrier(0);
    asm volatile("s_waitcnt vmcnt(0)" ::: "memory");
    __builtin_amdgcn_sched_barrier(0);
    {
        v8s a0 = *(const v8s*)&sa[wv][2][r16][((g) ^ xk) * 8];
        v8s b0 = *(const v8s*)&scrow[11 * 64 + g * 8];
        acc = __builtin_amdgcn_mfma_f32_16x16x32_bf16(a0, b0, acc, 0, 0, 0);
        v8s a1 = *(const v8s*)&sa[wv][2][r16][((4 + g) ^ xk) * 8];
        v8s b1 = *(const v8s*)&scrow[11 * 64 + 32 + g * 8];
        acc = __builtin_amdgcn_mfma_f32_16x16x32_bf16(a1, b1, acc, 0, 0, 0);
    }

    __syncthreads();   // all waves' sc2 visible

    // epilogue: argmax always; softmax+out only on compare pass
    float cxv = scx[r16], cyv = scy[r16], c2v = sc2[r16];
    #pragma unroll
    for (int j = 0; j < 4; ++j) {
        int lr = wv * 16 + g * 4 + j;
        int p = pb * 96 + lr;
        float px = (float)(p % SGRID) * COMPF;
        float py = (float)(p / SGRID) * COMPF;
        float lg = 2.f * (acc[j] + px * cxv + py * cyv) - c2v;
        float mx = lg;
        mx = fmaxf(mx, __shfl_xor(mx, 1));
        mx = fmaxf(mx, __shfl_xor(mx, 2));
        mx = fmaxf(mx, __shfl_xor(mx, 4));
        mx = fmaxf(mx, __shfl_xor(mx, 8));
        if (!itFirst) {
            float e = __expf(lg - mx);
            float se = e;
            se += __shfl_xor(se, 1);
            se += __shfl_xor(se, 2);
            se += __shfl_xor(se, 4);
            se += __shfl_xor(se, 8);
            if (r16 < NK) out[((size_t)b * NP + p) * NK + r16] = e / se;
        }
        unsigned long long wm = __ballot(lg == mx);
        int ki = (int)(__ffsll((unsigned long long)((wm >> (lane & 48)) & 0xFFFFull)) - 1);
        if (r16 == 0) swin[lr] = (unsigned char)ki;
    }
    __syncthreads();   // swin complete

    // convergence compare (wave 1, two 48-point halves)
    if (wv == 1) {
        unsigned char* prevb = prev + (size_t)b * NP + pb * 96;
        unsigned char n0 = swin[lane < 48 ? lane : 0];
        unsigned char n1 = swin[lane < 48 ? 48 + lane : 48];
        bool d0 = false, d1 = false;
        if (lane < 48) {
            if (!itFirst) { d0 = (prevb[lane] != n0); d1 = (prevb[48 + lane] != n1); }
            prevb[lane] = n0; prevb[48 + lane] = n1;
        }
        unsigned long long dm = __ballot(d0 || d1);
        if (lane == 0 && !itFirst && dm != 0ull) { chgflag[b] = 1; tileChg = 1; }
    }
    // per-cluster lists (wave 0, two 48-point halves, stable order)
    if (wv == 0) {
        int k0 = (lane < 48) ? (int)swin[lane] : 255;
        int k1 = (lane < 48) ? (int)swin[48 + lane] : 255;
        unsigned long long lmask = (1ull << lane) - 1ull;
        #pragma unroll
        for (int kk = 0; kk < NK; ++kk) {
            unsigned long long m0 = __ballot(k0 == kk);
            unsigned long long m1 = __ballot(k1 == kk);
            int c0 = __popcll(m0);
            if (k0 == kk) splist[kk][__popcll(m0 & lmask)] = (unsigned char)lane;
            if (k1 == kk) splist[kk][c0 + __popcll(m1 & lmask)] = (unsigned char)(48 + lane);
            if (lane == 0) scnt[kk] = c0 + __popcll(m1);
        }
    }
    __syncthreads();   // lists + tileChg final

    // partial update: skipped when this tile's assignment is unchanged
    // (pcent then already holds bit-identical values from the A_0 pass)
    if (tileChg) {
        float* pc = pcent + (size_t)(b * 9 + pb) * NK * CSTR;   // 9-tile item stride!
        if (t < NK) {
            int n = scnt[t];
            float sx = 0.f, sy = 0.f;
            for (int i = 0; i < n; ++i) {
                int p = pb * 96 + splist[t][i];
                sx += (float)(p % SGRID);
                sy += (float)(p / SGRID);
            }
            pc[t * CSTR + 768] = sx * COMPF;
            pc[t * CSTR + 769] = sy * COMPF;
            pc[t * CSTR + 770] = (float)scnt[t];
        }
        // all 384 threads: thread t owns channels 2t, 2t+1
        const unsigned short* e2 = eg + 2 * t;
        #pragma unroll
        for (int k = 0; k < NK; ++k) {
            int n = scnt[k];
            float a0 = 0.f, a1 = 0.f;
            for (int i = 0; i < n; ++i) {
                int p = splist[k][i];
                ushort2 u = *(const ushort2*)(e2 + (size_t)p * EMB);
                a0 += b2f(u.x); a1 += b2f(u.y);
            }
            *(float2*)&pc[k * CSTR + 2 * t] = make_float2(a0, a1);
        }
    }
}

// ---------------- reduce: nt partials -> bf16 centroids + csp ----------------
__global__ __launch_bounds__(256) void reduce_k(const float* __restrict__ pcent,
                                                unsigned short* __restrict__ centb,
                                                float* __restrict__ csp, int nt) {
    __shared__ float sw[NK];
    int b = blockIdx.x / 3, cb = blockIdx.x % 3;
    int t = threadIdx.x;
    const float* pc = pcent + (size_t)b * 9 * NK * CSTR;   // 9-tile item stride

    if (t < NK) {
        float w = 0.f, sx = 0.f, sy = 0.f;
        for (int s = 0; s < nt; ++s) {
            const float* q = pc + (size_t)(s * NK + t) * CSTR;
            sx += q[768]; sy += q[769]; w += q[770];
        }
        float wi = w + EPSV;
        sw[t] = wi;
        if (cb == 0) {
            csp[((size_t)b * NK + t) * 2 + 0] = sx / wi;
            csp[((size_t)b * NK + t) * 2 + 1] = sy / wi;
        }
    }
    __syncthreads();

    int c = cb * 256 + t;
    #pragma unroll
    for (int k = 0; k < NK; ++k) {
        float v = 0.f;
        for (int s = 0; s < nt; ++s) v += pc[(size_t)(s * NK + k) * CSTR + c];
        centb[((size_t)b * NK + k) * EMB + c] = f2b(v / sw[k]);
    }
}

// ---------------- tail: persistent per-item finisher (stub when converged) --
__global__ __launch_bounds__(576) void tail_k(
    const unsigned short* __restrict__ embb,
    const float* __restrict__ pcent,           // slots 0..5 of 9-tile regions
    const unsigned char* __restrict__ prevg,
    const int* __restrict__ chgflag,
    float* __restrict__ out)
{
    __shared__ unsigned short sc[16][776];
    __shared__ unsigned short sa[3][2][48][64];
    __shared__ float cacc[NK][EMB];
    __shared__ float cw[NK], csx[NK], csy[NK];
    __shared__ float scx[16], scy[16], sc2[16];
    __shared__ unsigned char prev[NP];
    __shared__ unsigned char swin[3][48];
    __shared__ unsigned char splist[3][NK][48];
    __shared__ int scnt[3][NK];
    __shared__ int chg;

    int b = blockIdx.x;
    if (chgflag[b] == 0) return;

    int t = threadIdx.x, lane = t & 63, wv = t >> 6;
    int grp = wv / 3, wg = wv % 3, gt = t - grp * 192;
    int r16 = lane & 15, g = lane >> 4;
    const unsigned short* ib = embb + (size_t)b * NP * EMB;

    for (int i = t; i < 7 * 96; i += 576) {
        int k = 9 + i / 96, s = i % 96;
        v8s z = {0,0,0,0,0,0,0,0};
        *(v8s*)&sc[k][s * 8] = z;
    }
    if (t >= NK && t < 16) { scx[t] = 0.f; scy[t] = 0.f; sc2[t] = 1e30f; }
    for (int i = t; i < NP; i += 576) prev[i] = prevg[(size_t)b * NP + i];

    const float* pcb = pcent + (size_t)b * 9 * NK * CSTR;
    if (t < 192) {
        int ch = t * 4;
        #pragma unroll
        for (int k = 0; k < NK; ++k) {
            float4 s = make_float4(0.f, 0.f, 0.f, 0.f);
            #pragma unroll
            for (int s9 = 0; s9 < 6; ++s9) {
                float4 q = *(const float4*)&pcb[(size_t)(s9 * NK + k) * CSTR + ch];
                s.x += q.x; s.y += q.y; s.z += q.z; s.w += q.w;
            }
            cacc[k][ch] = s.x; cacc[k][ch+1] = s.y; cacc[k][ch+2] = s.z; cacc[k][ch+3] = s.w;
        }
    }
    if (t < NK) {
        float w = 0.f, sx = 0.f, sy = 0.f;
        for (int s9 = 0; s9 < 6; ++s9) {
            const float* q = pcb + (size_t)(s9 * NK + t) * CSTR;
            sx += q[768]; sy += q[769]; w += q[770];
        }
        cw[t] = w; csx[t] = sx; csy[t] = sy;
    }
    __syncthreads();

    for (int it = 2; it <= NITER; ++it) {
        bool lastPass = (it == NITER);

        if (t < 192) {
            int ch = t * 4;
            #pragma unroll
            for (int k = 0; k < NK; ++k) {
                float inv = 1.f / (cw[k] + EPSV);
                ushort4 u;
                u.x = f2b(cacc[k][ch] * inv);
                u.y = f2b(cacc[k][ch+1] * inv);
                u.z = f2b(cacc[k][ch+2] * inv);
                u.w = f2b(cacc[k][ch+3] * inv);
                *(ushort4*)&sc[k][ch] = u;
            }
        }
        if (t < NK) {
            float inv = 1.f / (cw[t] + EPSV);
            scx[t] = csx[t] * inv;
            scy[t] = csy[t] * inv;
        }
        __syncthreads();

        if (wv < NK) {
            float s = 0.f;
            const unsigned short* ck = sc[wv];
            #pragma unroll
            for (int c = 0; c < EMB / 64; ++c) {
                float v = b2f(ck[lane + c * 64]); s += v * v;
            }
            #pragma unroll
            for (int m = 1; m < 64; m <<= 1) s += __shfl_xor(s, m);
            if (lane == 0) sc2[wv] = s + scx[wv] * scx[wv] + scy[wv] * scy[wv];
        }
        for (int i = t; i < NK * EMB; i += 576) ((float*)cacc)[i] = 0.f;
        if (t < NK) { cw[t] = 0.f; csx[t] = 0.f; csy[t] = 0.f; }
        if (t == 0) chg = 0;
        __syncthreads();

        float acc2[NK][4];
        #pragma unroll
        for (int k = 0; k < NK; ++k) { acc2[k][0]=0.f; acc2[k][1]=0.f; acc2[k][2]=0.f; acc2[k][3]=0.f; }
        float wreg = 0.f, sxreg = 0.f, syreg = 0.f;

        for (int rd = 0; rd < 4; ++rd) {
            int tileBase = (rd * 3 + grp) * 48;
            int sr = gt >> 3, sl = gt & 7;
            int sphys = (sl ^ (sr & 7)) * 8;
            const unsigned short* gb = ib + (size_t)(tileBase + sr) * EMB + sl * 8;
            v8s s0 = *(const v8s*)(gb);
            v8s s1 = *(const v8s*)(gb + 24 * EMB);
            *(v8s*)&sa[grp][0][sr][sphys] = s0;
            *(v8s*)&sa[grp][0][sr + 24][sphys] = s1;

            v4f acc = {0.f, 0.f, 0.f, 0.f};
            int lrow = wg * 16 + r16;
            for (int cn = 0; cn < 12; ++cn) {
                v8s n0, n1;
                if (cn < 11) {
                    n0 = *(const v8s*)(gb + (cn + 1) * 64);
                    n1 = *(const v8s*)(gb + (cn + 1) * 64 + 24 * EMB);
                }
                __syncthreads();
                int cur = cn & 1;
                #pragma unroll
                for (int ks = 0; ks < 2; ++ks) {
                    v8s af = *(const v8s*)&sa[grp][cur][lrow][(((ks << 2) + g) ^ (r16 & 7)) << 3];
                    v8s bf = *(const v8s*)&sc[r16][cn * 64 + ks * 32 + g * 8];
                    acc = __builtin_amdgcn_mfma_f32_16x16x32_bf16(af, bf, acc, 0, 0, 0);
                }
                if (cn < 11) {
                    *(v8s*)&sa[grp][cur ^ 1][sr][sphys] = n0;
                    *(v8s*)&sa[grp][cur ^ 1][sr + 24][sphys] = n1;
                }
            }

            float cxv = scx[r16], cyv = scy[r16], c2v = sc2[r16];
            #pragma unroll
            for (int j = 0; j < 4; ++j) {
                int lr = wg * 16 + g * 4 + j;
                int p = tileBase + lr;
                float px = (float)(p % SGRID) * COMPF;
                float py = (float)(p / SGRID) * COMPF;
                float lg = 2.f * (acc[j] + px * cxv + py * cyv) - c2v;
                float mx = lg;
                mx = fmaxf(mx, __shfl_xor(mx, 1));
                mx = fmaxf(mx, __shfl_xor(mx, 2));
                mx = fmaxf(mx, __shfl_xor(mx, 4));
                mx = fmaxf(mx, __shfl_xor(mx, 8));
                float e = __expf(lg - mx);
                float se = e;
                se += __shfl_xor(se, 1);
                se += __shfl_xor(se, 2);
                se += __shfl_xor(se, 4);
                se += __shfl_xor(se, 8);
                if (r16 < NK) out[((size_t)b * NP + p) * NK + r16] = e / se;
                if (!lastPass) {
                    float m = lg; int ki = r16;
                    #pragma unroll
                    for (int d = 1; d < 16; d <<= 1) {
                        float om = __shfl_xor(m, d);
                        int oi = __shfl_xor(ki, d);
                        if (om > m || (om == m && oi < ki)) { m = om; ki = oi; }
                    }
                    if (r16 == 0) swin[grp][lr] = (unsigned char)ki;
                }
            }

            if (!lastPass) {
                __syncthreads();
                if (wg == 0) {
                    unsigned char myk = swin[grp][lane < 48 ? lane : 0];
                    bool diff = false;
                    if (lane < 48) {
                        int p = tileBase + lane;
                        diff = (prev[p] != myk);
                        prev[p] = myk;
                    }
                    unsigned long long dm = __ballot(diff);
                    if (lane == 0 && dm != 0ull) chg = 1;
                    unsigned long long lmask = (1ull << lane) - 1ull;
                    #pragma unroll
                    for (int kk = 0; kk < NK; ++kk) {
                        unsigned long long msk = __ballot(lane < 48 && myk == (unsigned char)kk);
                        int pos = __popcll(msk & lmask);
                        if (lane < 48 && myk == (unsigned char)kk)
                            splist[grp][kk][pos] = (unsigned char)lane;
                        if (lane == 0) scnt[grp][kk] = __popcll(msk);
                    }
                }
                __syncthreads();

                if (wg == 0 && lane < NK) {
                    int n = scnt[grp][lane];
                    float sx = 0.f, sy = 0.f;
                    for (int i = 0; i < n; ++i) {
                        int p = tileBase + splist[grp][lane][i];
                        sx += (float)(p % SGRID);
                        sy += (float)(p / SGRID);
                    }
                    wreg += (float)n; sxreg += sx; syreg += sy;
                }
                const unsigned short* e2 = ib + (size_t)tileBase * EMB + gt * 4;
                #pragma unroll
                for (int k = 0; k < NK; ++k) {
                    int n = scnt[grp][k];
                    float a0 = acc2[k][0], a1 = acc2[k][1], a2 = acc2[k][2], a3 = acc2[k][3];
                    for (int i = 0; i < n; ++i) {
                        int row = splist[grp][k][i];
                        ushort4 u = *(const ushort4*)(e2 + (size_t)row * EMB);
                        a0 += b2f(u.x); a1 += b2f(u.y); a2 += b2f(u.z); a3 += b2f(u.w);
                    }
                    acc2[k][0] = a0; acc2[k][1] = a1; acc2[k][2] = a2; acc2[k][3] = a3;
                }
            }
        }

        if (lastPass) break;
        if (chg == 0) break;

        for (int g3 = 0; g3 < 3; ++g3) {
            if (grp == g3) {
                int ch = gt * 4;
                #pragma unroll
                for (int k = 0; k < NK; ++k) {
                    cacc[k][ch]   += acc2[k][0];
                    cacc[k][ch+1] += acc2[k][1];
                    cacc[k][ch+2] += acc2[k][2];
                    cacc[k][ch+3] += acc2[k][3];
                }
                if (wg == 0 && lane < NK) {
                    cw[lane]  += wreg;
                    csx[lane] += sxreg * COMPF;
                    csy[lane] += syreg * COMPF;
                }
            }
            __syncthreads();
        }
    }
}

extern "C" void kernel_launch(void* const* d_in, const int* in_sizes, int n_in,
                              void* d_out, int out_size, void* d_ws, size_t ws_size,
                              hipStream_t stream) {
    const float* emb = (const float*)d_in[0];
    char* w = (char*)d_ws;
    unsigned short* embb = (unsigned short*)w;  w += (size_t)NB * NP * EMB * 2;
    float* pcent = (float*)w;                   w += (size_t)NB * 9 * NK * CSTR * 4;
    unsigned short* centb = (unsigned short*)w; w += (size_t)NB * NK * EMB * 2;
    float* csp = (float*)w;                     w += (size_t)NB * NK * 2 * 4;
    unsigned char* prev = (unsigned char*)w;    w += (size_t)NB * NP;
    int* chgflag = (int*)w;                     w += (size_t)NB * 4;

    init_k<<<NB * 9, 192, 0, stream>>>(emb, embb, pcent, chgflag);
    reduce_k<<<NB * 3, 256, 0, stream>>>(pcent, centb, csp, 9);
    fused_k<<<NB * 6, 384, 0, stream>>>(embb, centb, csp, pcent, prev, chgflag, 1, (float*)d_out);
    reduce_k<<<NB * 3, 256, 0, stream>>>(pcent, centb, csp, 6);
    fused_k<<<NB * 6, 384, 0, stream>>>(embb, centb, csp, pcent, prev, chgflag, 0, (float*)d_out);
    tail_k<<<NB, 576, 0, stream>>>(embb, pcent, prev, chgflag, (float*)d_out);
}

// Round 12
// 169.301 us; speedup vs baseline: 1.1564x; 1.1564x over previous
//
#include <hip/hip_runtime.h>

#define NB 128
#define NP 576
#define NK 9
#define EMB 768
#define SGRID 24
#define COMPF 3.0f
#define NITER 10
#define EPSV 1e-8f

typedef short v8s __attribute__((ext_vector_type(8)));
typedef float v4f __attribute__((ext_vector_type(4)));

__device__ __forceinline__ unsigned short f2b(float f) {
    unsigned x = __float_as_uint(f);
    unsigned r = (x + 0x7fffu + ((x >> 16) & 1u)) >> 16;
    return (unsigned short)r;
}
__device__ __forceinline__ float b2f(unsigned short u) {
    return __uint_as_float(((unsigned)u) << 16);
}

// async global->LDS, 16B per lane: dest = wave-uniform base + lane*16
__device__ __forceinline__ void gload16(const unsigned short* g, unsigned short* l) {
    __builtin_amdgcn_global_load_lds(
        (const __attribute__((address_space(1))) unsigned int*)g,
        (__attribute__((address_space(3))) unsigned int*)l, 16, 0, 0);
}

// ---------------- init: fp32->bf16 conversion + indicator partials ----------
// 9 tiles of 64 points per item. Partials bf16, meta (sx,sy,w) fp32.
__global__ __launch_bounds__(192) void init_k(const float* __restrict__ emb,
                                              unsigned short* __restrict__ embb,
                                              unsigned short* __restrict__ pcb,
                                              float* __restrict__ pmeta,
                                              int* __restrict__ chgflag) {
    int blk = blockIdx.x, b = blk / 9, pb = blk % 9;
    int t = threadIdx.x;
    int ay = pb / 3;

    if (pb == 0 && t == 0) chgflag[b] = 0;

    float a0x=0,a0y=0,a0z=0,a0w=0, a1x=0,a1y=0,a1z=0,a1w=0, a2x=0,a2y=0,a2z=0,a2w=0;
    const float* eg = emb + ((size_t)b * NP + pb * 64) * EMB + t * 4;
    unsigned short* og = embb + ((size_t)b * NP + pb * 64) * EMB + t * 4;
    for (int p = 0; p < 64; ++p) {
        float4 f = *(const float4*)(eg + (size_t)p * EMB);
        ushort4 u;
        u.x = f2b(f.x); u.y = f2b(f.y); u.z = f2b(f.z); u.w = f2b(f.w);
        *(ushort4*)(og + (size_t)p * EMB) = u;
        int pg = pb * 64 + p;
        int sel = (pg % SGRID) >> 3;
        bool m0 = (sel == 0), m1 = (sel == 1), m2 = (sel == 2);
        a0x += m0 ? f.x : 0.f; a0y += m0 ? f.y : 0.f; a0z += m0 ? f.z : 0.f; a0w += m0 ? f.w : 0.f;
        a1x += m1 ? f.x : 0.f; a1y += m1 ? f.y : 0.f; a1z += m1 ? f.z : 0.f; a1w += m1 ? f.w : 0.f;
        a2x += m2 ? f.x : 0.f; a2y += m2 ? f.y : 0.f; a2z += m2 ? f.z : 0.f; a2w += m2 ? f.w : 0.f;
    }
    unsigned short* pc = pcb + (size_t)(b * 9 + pb) * NK * EMB;
    #pragma unroll
    for (int k = 0; k < NK; ++k) {
        int s = k - ay * 3;
        float vx = 0.f, vy = 0.f, vz = 0.f, vw = 0.f;
        if (s == 0) { vx = a0x; vy = a0y; vz = a0z; vw = a0w; }
        if (s == 1) { vx = a1x; vy = a1y; vz = a1z; vw = a1w; }
        if (s == 2) { vx = a2x; vy = a2y; vz = a2z; vw = a2w; }
        ushort4 u;
        u.x = f2b(vx); u.y = f2b(vy); u.z = f2b(vz); u.w = f2b(vw);
        *(ushort4*)&pc[k * EMB + t * 4] = u;
    }
    if (t < NK) {
        int s = t - ay * 3;
        float w = 0.f, sx = 0.f, sy = 0.f;
        if (s >= 0 && s < 3) {
            for (int p = 0; p < 64; ++p) {
                int pg = pb * 64 + p;
                if (((pg % SGRID) >> 3) == s) {
                    w += 1.f;
                    sx += (float)(pg % SGRID) * COMPF;
                    sy += (float)(pg / SGRID) * COMPF;
                }
            }
        }
        *(float4*)&pmeta[((size_t)(b * 9 + pb) * NK + t) * 4] =
            make_float4(sx, sy, w, 0.f);
    }
}

// ---------------- fused: barrier-free MFMA assign + WTA partial update ------
// grid NB*9, 256 thr (4 waves), 64-pt tiles (round-9 proven structure).
// Wave-private A staging via global_load_lds 3-slot ring, counted vmcnt(2).
__global__ __launch_bounds__(256) void fused_k(
    const unsigned short* __restrict__ embb,
    const unsigned short* __restrict__ centb,
    const float* __restrict__ csp,
    unsigned short* __restrict__ pcb,          // [NB][9][NK][EMB] bf16
    float* __restrict__ pmeta,                 // [NB][9][NK][4] {sx,sy,w,_}
    unsigned char* __restrict__ prev,
    int* __restrict__ chgflag,
    int itFirst,              // 1: A_0 pass (no out); 0: compare + softmax out
    float* __restrict__ out)
{
    __shared__ unsigned short sc[16][776];                  // B operand (+pad)
    __shared__ __align__(16) unsigned short sa[4][3][16][64]; // [wave][slot][row][ch]
    __shared__ float scx[16], scy[16], sc2[16];
    __shared__ int swin[64];
    __shared__ int scnt[NK];
    __shared__ unsigned char splist[NK][64];
    __shared__ int tileChg;

    int blk = blockIdx.x;
    int b = blk / 9, pb = blk % 9;
    int t = threadIdx.x, lane = t & 63, wv = t >> 6;
    int r16 = lane & 15, g = lane >> 4;

    // stage centroids (B), zero-pad clusters 9..15
    const unsigned short* cg = centb + (size_t)b * NK * EMB;
    for (int i = t; i < NK * 96; i += 256) {
        int k = i / 96, s = i % 96;
        *(v8s*)&sc[k][s * 8] = *(const v8s*)&cg[k * EMB + s * 8];
    }
    for (int i = t; i < 7 * 96; i += 256) {
        int k = 9 + i / 96, s = i % 96;
        v8s z = {0,0,0,0,0,0,0,0};
        *(v8s*)&sc[k][s * 8] = z;
    }
    if (t < 16) {
        scx[t] = (t < NK) ? csp[((size_t)b * NK + t) * 2 + 0] : 0.f;
        scy[t] = (t < NK) ? csp[((size_t)b * NK + t) * 2 + 1] : 0.f;
    }
    if (t == 0) tileChg = itFirst;

    // per-lane pre-swizzled global source
    const unsigned short* eg = embb + ((size_t)b * NP + pb * 64) * EMB;
    const unsigned short* gb = eg + (size_t)(wv * 16 + (lane >> 3)) * EMB
                                  + (size_t)(((lane & 7) ^ (lane >> 3)) * 8);

    // prologue: chunks 0,1 into slots 0,1
    gload16(gb,                 &sa[wv][0][0][0]);
    gload16(gb + 8 * EMB,       &sa[wv][0][8][0]);
    gload16(gb + 64,            &sa[wv][1][0][0]);
    gload16(gb + 8 * EMB + 64,  &sa[wv][1][8][0]);

    __syncthreads();   // sc/scx/scy staged

    // c2 from staged bf16 centroids — wave 0
    if (wv == 0) {
        for (int k = 0; k < NK; ++k) {
            float s = 0.f;
            const unsigned short* ck = sc[k];
            for (int c = lane; c < EMB; c += 64) { float v = b2f(ck[c]); s += v * v; }
            #pragma unroll
            for (int m = 1; m < 64; m <<= 1) s += __shfl_xor(s, m);
            if (lane == 0) sc2[k] = s + scx[k] * scx[k] + scy[k] * scy[k];
        }
        if (lane >= NK && lane < 16) sc2[lane] = 1e30f;
    }

    // K-loop: 12 chunks of 64ch, wave-private, zero barriers
    v4f acc = {0.f, 0.f, 0.f, 0.f};
    const unsigned short* scrow = sc[r16];
    int xk = r16 & 7;

    #pragma unroll
    for (int cn = 0; cn < 11; ++cn) {
        __builtin_amdgcn_sched_barrier(0);
        asm volatile("s_waitcnt vmcnt(2)" ::: "memory");   // chunk cn staged
        __builtin_amdgcn_sched_barrier(0);
        if (cn < 10) {
            int sl = (cn + 2) % 3;
            gload16(gb + (cn + 2) * 64,           &sa[wv][sl][0][0]);
            gload16(gb + 8 * EMB + (cn + 2) * 64, &sa[wv][sl][8][0]);
        }
        int cur = cn % 3;
        v8s a0 = *(const v8s*)&sa[wv][cur][r16][((g) ^ xk) * 8];
        v8s b0 = *(const v8s*)&scrow[cn * 64 + g * 8];
        acc = __builtin_amdgcn_mfma_f32_16x16x32_bf16(a0, b0, acc, 0, 0, 0);
        v8s a1 = *(const v8s*)&sa[wv][cur][r16][((4 + g) ^ xk) * 8];
        v8s b1 = *(const v8s*)&scrow[cn * 64 + 32 + g * 8];
        acc = __builtin_amdgcn_mfma_f32_16x16x32_bf16(a1, b1, acc, 0, 0, 0);
    }
    __builtin_amdgcn_sched_barrier(0);
    asm volatile("s_waitcnt vmcnt(0)" ::: "memory");
    __builtin_amdgcn_sched_barrier(0);
    {
        v8s a0 = *(const v8s*)&sa[wv][2][r16][((g) ^ xk) * 8];
        v8s b0 = *(const v8s*)&scrow[11 * 64 + g * 8];
        acc = __builtin_amdgcn_mfma_f32_16x16x32_bf16(a0, b0, acc, 0, 0, 0);
        v8s a1 = *(const v8s*)&sa[wv][2][r16][((4 + g) ^ xk) * 8];
        v8s b1 = *(const v8s*)&scrow[11 * 64 + 32 + g * 8];
        acc = __builtin_amdgcn_mfma_f32_16x16x32_bf16(a1, b1, acc, 0, 0, 0);
    }

    __syncthreads();   // all waves' sc2 visible

    // epilogue: argmax always; softmax+out only on compare pass
    float cxv = scx[r16], cyv = scy[r16], c2v = sc2[r16];
    #pragma unroll
    for (int j = 0; j < 4; ++j) {
        int lr = wv * 16 + g * 4 + j;
        int p = pb * 64 + lr;
        float px = (float)(p % SGRID) * COMPF;
        float py = (float)(p / SGRID) * COMPF;
        float lg = 2.f * (acc[j] + px * cxv + py * cyv) - c2v;
        float mx = lg;
        mx = fmaxf(mx, __shfl_xor(mx, 1));
        mx = fmaxf(mx, __shfl_xor(mx, 2));
        mx = fmaxf(mx, __shfl_xor(mx, 4));
        mx = fmaxf(mx, __shfl_xor(mx, 8));
        if (!itFirst) {
            float e = __expf(lg - mx);
            float se = e;
            se += __shfl_xor(se, 1);
            se += __shfl_xor(se, 2);
            se += __shfl_xor(se, 4);
            se += __shfl_xor(se, 8);
            if (r16 < NK) out[((size_t)b * NP + p) * NK + r16] = e / se;
        }
        unsigned long long wm = __ballot(lg == mx);
        int ki = (int)(__ffsll((unsigned long long)((wm >> (lane & 48)) & 0xFFFFull)) - 1);
        if (r16 == 0) swin[lr] = ki;
    }
    __syncthreads();   // swin complete

    // convergence compare (wave 1) + per-cluster lists (all waves)
    if (wv == 1) {
        unsigned char* prevb = prev + (size_t)b * NP + pb * 64;
        unsigned char neww = (unsigned char)swin[lane];
        if (!itFirst) {
            bool diff = (prevb[lane] != neww);
            unsigned long long m = __ballot(diff);
            if (lane == 0 && m != 0ull) { chgflag[b] = 1; tileChg = 1; }
        }
        prevb[lane] = neww;
    }
    {
        int myk = swin[lane];
        for (int kk = wv; kk < NK; kk += 4) {
            unsigned long long msk = __ballot(myk == kk);
            int pos = __popcll(msk & ((1ull << lane) - 1ull));
            if (myk == kk) splist[kk][pos] = (unsigned char)lane;
            if (lane == 0) scnt[kk] = __popcll(msk);
        }
    }
    __syncthreads();   // lists + tileChg final

    // partial update: skipped when this tile's assignment is unchanged
    if (tileChg) {
        if (t < NK) {
            int n = scnt[t];
            float sx = 0.f, sy = 0.f;
            for (int i = 0; i < n; ++i) {
                int p = pb * 64 + splist[t][i];
                sx += (float)(p % SGRID);
                sy += (float)(p / SGRID);
            }
            *(float4*)&pmeta[((size_t)(b * 9 + pb) * NK + t) * 4] =
                make_float4(sx * COMPF, sy * COMPF, (float)n, 0.f);
        }
        if (t < 192) {
            unsigned short* pcw = pcb + (size_t)(b * 9 + pb) * NK * EMB;
            const unsigned short* e2 = eg + 4 * t;
            #pragma unroll
            for (int k = 0; k < NK; ++k) {
                int n = scnt[k];
                float a0 = 0.f, a1 = 0.f, a2 = 0.f, a3 = 0.f;
                for (int i = 0; i < n; ++i) {
                    int p = splist[k][i];
                    ushort4 u = *(const ushort4*)(e2 + (size_t)p * EMB);
                    a0 += b2f(u.x); a1 += b2f(u.y); a2 += b2f(u.z); a3 += b2f(u.w);
                }
                ushort4 o;
                o.x = f2b(a0); o.y = f2b(a1); o.z = f2b(a2); o.w = f2b(a3);
                *(ushort4*)&pcw[k * EMB + t * 4] = o;
            }
        }
    }
}

// ---------------- reduce: 9 bf16 partials -> bf16 centroids + csp -----------
__global__ __launch_bounds__(256) void reduce_k(const unsigned short* __restrict__ pcb,
                                                const float* __restrict__ pmeta,
                                                unsigned short* __restrict__ centb,
                                                float* __restrict__ csp) {
    __shared__ float sw[NK];
    int b = blockIdx.x / 3, cb = blockIdx.x % 3;
    int t = threadIdx.x;
    const unsigned short* pc = pcb + (size_t)b * 9 * NK * EMB;
    const float* pm = pmeta + (size_t)b * 9 * NK * 4;

    if (t < NK) {
        float w = 0.f, sx = 0.f, sy = 0.f;
        for (int s = 0; s < 9; ++s) {
            const float* q = pm + (size_t)(s * NK + t) * 4;
            sx += q[0]; sy += q[1]; w += q[2];
        }
        float wi = w + EPSV;
        sw[t] = wi;
        if (cb == 0) {
            csp[((size_t)b * NK + t) * 2 + 0] = sx / wi;
            csp[((size_t)b * NK + t) * 2 + 1] = sy / wi;
        }
    }
    __syncthreads();

    int c = cb * 256 + t;
    #pragma unroll
    for (int k = 0; k < NK; ++k) {
        float v = 0.f;
        #pragma unroll
        for (int s = 0; s < 9; ++s) v += b2f(pc[(size_t)(s * NK + k) * EMB + c]);
        centb[((size_t)b * NK + k) * EMB + c] = f2b(v / sw[k]);
    }
}

// ---------------- tail: persistent per-item finisher (stub when converged) --
__global__ __launch_bounds__(576) void tail_k(
    const unsigned short* __restrict__ embb,
    const unsigned short* __restrict__ pcb,
    const float* __restrict__ pmeta,
    const unsigned char* __restrict__ prevg,
    const int* __restrict__ chgflag,
    float* __restrict__ out)
{
    __shared__ unsigned short sc[16][776];
    __shared__ unsigned short sa[3][2][48][64];
    __shared__ float cacc[NK][EMB];
    __shared__ float cw[NK], csx[NK], csy[NK];
    __shared__ float scx[16], scy[16], sc2[16];
    __shared__ unsigned char prev[NP];
    __shared__ unsigned char swin[3][48];
    __shared__ unsigned char splist[3][NK][48];
    __shared__ int scnt[3][NK];
    __shared__ int chg;

    int b = blockIdx.x;
    if (chgflag[b] == 0) return;

    int t = threadIdx.x, lane = t & 63, wv = t >> 6;
    int grp = wv / 3, wg = wv % 3, gt = t - grp * 192;
    int r16 = lane & 15, g = lane >> 4;
    const unsigned short* ib = embb + (size_t)b * NP * EMB;

    for (int i = t; i < 7 * 96; i += 576) {
        int k = 9 + i / 96, s = i % 96;
        v8s z = {0,0,0,0,0,0,0,0};
        *(v8s*)&sc[k][s * 8] = z;
    }
    if (t >= NK && t < 16) { scx[t] = 0.f; scy[t] = 0.f; sc2[t] = 1e30f; }
    for (int i = t; i < NP; i += 576) prev[i] = prevg[(size_t)b * NP + i];

    const unsigned short* pcb16 = pcb + (size_t)b * 9 * NK * EMB;
    const float* pmb = pmeta + (size_t)b * 9 * NK * 4;
    if (t < 192) {
        int ch = t * 4;
        #pragma unroll
        for (int k = 0; k < NK; ++k) {
            float s0 = 0.f, s1 = 0.f, s2 = 0.f, s3 = 0.f;
            #pragma unroll
            for (int s9 = 0; s9 < 9; ++s9) {
                ushort4 q = *(const ushort4*)&pcb16[(size_t)(s9 * NK + k) * EMB + ch];
                s0 += b2f(q.x); s1 += b2f(q.y); s2 += b2f(q.z); s3 += b2f(q.w);
            }
            cacc[k][ch] = s0; cacc[k][ch+1] = s1; cacc[k][ch+2] = s2; cacc[k][ch+3] = s3;
        }
    }
    if (t < NK) {
        float w = 0.f, sx = 0.f, sy = 0.f;
        for (int s9 = 0; s9 < 9; ++s9) {
            const float* q = pmb + (size_t)(s9 * NK + t) * 4;
            sx += q[0]; sy += q[1]; w += q[2];
        }
        cw[t] = w; csx[t] = sx; csy[t] = sy;
    }
    __syncthreads();

    for (int it = 2; it <= NITER; ++it) {
        bool lastPass = (it == NITER);

        if (t < 192) {
            int ch = t * 4;
            #pragma unroll
            for (int k = 0; k < NK; ++k) {
                float inv = 1.f / (cw[k] + EPSV);
                ushort4 u;
                u.x = f2b(cacc[k][ch] * inv);
                u.y = f2b(cacc[k][ch+1] * inv);
                u.z = f2b(cacc[k][ch+2] * inv);
                u.w = f2b(cacc[k][ch+3] * inv);
                *(ushort4*)&sc[k][ch] = u;
            }
        }
        if (t < NK) {
            float inv = 1.f / (cw[t] + EPSV);
            scx[t] = csx[t] * inv;
            scy[t] = csy[t] * inv;
        }
        __syncthreads();

        if (wv < NK) {
            float s = 0.f;
            const unsigned short* ck = sc[wv];
            #pragma unroll
            for (int c = 0; c < EMB / 64; ++c) {
                float v = b2f(ck[lane + c * 64]); s += v * v;
            }
            #pragma unroll
            for (int m = 1; m < 64; m <<= 1) s += __shfl_xor(s, m);
            if (lane == 0) sc2[wv] = s + scx[wv] * scx[wv] + scy[wv] * scy[wv];
        }
        for (int i = t; i < NK * EMB; i += 576) ((float*)cacc)[i] = 0.f;
        if (t < NK) { cw[t] = 0.f; csx[t] = 0.f; csy[t] = 0.f; }
        if (t == 0) chg = 0;
        __syncthreads();

        float acc2[NK][4];
        #pragma unroll
        for (int k = 0; k < NK; ++k) { acc2[k][0]=0.f; acc2[k][1]=0.f; acc2[k][2]=0.f; acc2[k][3]=0.f; }
        float wreg = 0.f, sxreg = 0.f, syreg = 0.f;

        for (int rd = 0; rd < 4; ++rd) {
            int tileBase = (rd * 3 + grp) * 48;
            int sr = gt >> 3, sl = gt & 7;
            int sphys = (sl ^ (sr & 7)) * 8;
            const unsigned short* gb = ib + (size_t)(tileBase + sr) * EMB + sl * 8;
            v8s s0 = *(const v8s*)(gb);
            v8s s1 = *(const v8s*)(gb + 24 * EMB);
            *(v8s*)&sa[grp][0][sr][sphys] = s0;
            *(v8s*)&sa[grp][0][sr + 24][sphys] = s1;

            v4f acc = {0.f, 0.f, 0.f, 0.f};
            int lrow = wg * 16 + r16;
            for (int cn = 0; cn < 12; ++cn) {
                v8s n0, n1;
                if (cn < 11) {
                    n0 = *(const v8s*)(gb + (cn + 1) * 64);
                    n1 = *(const v8s*)(gb + (cn + 1) * 64 + 24 * EMB);
                }
                __syncthreads();
                int cur = cn & 1;
                #pragma unroll
                for (int ks = 0; ks < 2; ++ks) {
                    v8s af = *(const v8s*)&sa[grp][cur][lrow][(((ks << 2) + g) ^ (r16 & 7)) << 3];
                    v8s bf = *(const v8s*)&sc[r16][cn * 64 + ks * 32 + g * 8];
                    acc = __builtin_amdgcn_mfma_f32_16x16x32_bf16(af, bf, acc, 0, 0, 0);
                }
                if (cn < 11) {
                    *(v8s*)&sa[grp][cur ^ 1][sr][sphys] = n0;
                    *(v8s*)&sa[grp][cur ^ 1][sr + 24][sphys] = n1;
                }
            }

            float cxv = scx[r16], cyv = scy[r16], c2v = sc2[r16];
            #pragma unroll
            for (int j = 0; j < 4; ++j) {
                int lr = wg * 16 + g * 4 + j;
                int p = tileBase + lr;
                float px = (float)(p % SGRID) * COMPF;
                float py = (float)(p / SGRID) * COMPF;
                float lg = 2.f * (acc[j] + px * cxv + py * cyv) - c2v;
                float mx = lg;
                mx = fmaxf(mx, __shfl_xor(mx, 1));
                mx = fmaxf(mx, __shfl_xor(mx, 2));
                mx = fmaxf(mx, __shfl_xor(mx, 4));
                mx = fmaxf(mx, __shfl_xor(mx, 8));
                float e = __expf(lg - mx);
                float se = e;
                se += __shfl_xor(se, 1);
                se += __shfl_xor(se, 2);
                se += __shfl_xor(se, 4);
                se += __shfl_xor(se, 8);
                if (r16 < NK) out[((size_t)b * NP + p) * NK + r16] = e / se;
                if (!lastPass) {
                    float m = lg; int ki = r16;
                    #pragma unroll
                    for (int d = 1; d < 16; d <<= 1) {
                        float om = __shfl_xor(m, d);
                        int oi = __shfl_xor(ki, d);
                        if (om > m || (om == m && oi < ki)) { m = om; ki = oi; }
                    }
                    if (r16 == 0) swin[grp][lr] = (unsigned char)ki;
                }
            }

            if (!lastPass) {
                __syncthreads();
                if (wg == 0) {
                    unsigned char myk = swin[grp][lane < 48 ? lane : 0];
                    bool diff = false;
                    if (lane < 48) {
                        int p = tileBase + lane;
                        diff = (prev[p] != myk);
                        prev[p] = myk;
                    }
                    unsigned long long dm = __ballot(diff);
                    if (lane == 0 && dm != 0ull) chg = 1;
                    unsigned long long lmask = (1ull << lane) - 1ull;
                    #pragma unroll
                    for (int kk = 0; kk < NK; ++kk) {
                        unsigned long long msk = __ballot(lane < 48 && myk == (unsigned char)kk);
                        int pos = __popcll(msk & lmask);
                        if (lane < 48 && myk == (unsigned char)kk)
                            splist[grp][kk][pos] = (unsigned char)lane;
                        if (lane == 0) scnt[grp][kk] = __popcll(msk);
                    }
                }
                __syncthreads();

                if (wg == 0 && lane < NK) {
                    int n = scnt[grp][lane];
                    float sx = 0.f, sy = 0.f;
                    for (int i = 0; i < n; ++i) {
                        int p = tileBase + splist[grp][lane][i];
                        sx += (float)(p % SGRID);
                        sy += (float)(p / SGRID);
                    }
                    wreg += (float)n; sxreg += sx; syreg += sy;
                }
                const unsigned short* e2 = ib + (size_t)tileBase * EMB + gt * 4;
                #pragma unroll
                for (int k = 0; k < NK; ++k) {
                    int n = scnt[grp][k];
                    float a0 = acc2[k][0], a1 = acc2[k][1], a2 = acc2[k][2], a3 = acc2[k][3];
                    for (int i = 0; i < n; ++i) {
                        int row = splist[grp][k][i];
                        ushort4 u = *(const ushort4*)(e2 + (size_t)row * EMB);
                        a0 += b2f(u.x); a1 += b2f(u.y); a2 += b2f(u.z); a3 += b2f(u.w);
                    }
                    acc2[k][0] = a0; acc2[k][1] = a1; acc2[k][2] = a2; acc2[k][3] = a3;
                }
            }
        }

        if (lastPass) break;
        if (chg == 0) break;

        for (int g3 = 0; g3 < 3; ++g3) {
            if (grp == g3) {
                int ch = gt * 4;
                #pragma unroll
                for (int k = 0; k < NK; ++k) {
                    cacc[k][ch]   += acc2[k][0];
                    cacc[k][ch+1] += acc2[k][1];
                    cacc[k][ch+2] += acc2[k][2];
                    cacc[k][ch+3] += acc2[k][3];
                }
                if (wg == 0 && lane < NK) {
                    cw[lane]  += wreg;
                    csx[lane] += sxreg * COMPF;
                    csy[lane] += syreg * COMPF;
                }
            }
            __syncthreads();
        }
    }
}

extern "C" void kernel_launch(void* const* d_in, const int* in_sizes, int n_in,
                              void* d_out, int out_size, void* d_ws, size_t ws_size,
                              hipStream_t stream) {
    const float* emb = (const float*)d_in[0];
    char* w = (char*)d_ws;
    unsigned short* embb = (unsigned short*)w;  w += (size_t)NB * NP * EMB * 2;      // 113.2 MB
    unsigned short* pcb = (unsigned short*)w;   w += (size_t)NB * 9 * NK * EMB * 2;  // 15.9 MB
    float* pmeta = (float*)w;                   w += (size_t)NB * 9 * NK * 4 * 4;    // 0.66 MB
    unsigned short* centb = (unsigned short*)w; w += (size_t)NB * NK * EMB * 2;      // 1.8 MB
    float* csp = (float*)w;                     w += (size_t)NB * NK * 2 * 4;
    unsigned char* prev = (unsigned char*)w;    w += (size_t)NB * NP;
    int* chgflag = (int*)w;                     w += (size_t)NB * 4;

    init_k<<<NB * 9, 192, 0, stream>>>(emb, embb, pcb, pmeta, chgflag);
    reduce_k<<<NB * 3, 256, 0, stream>>>(pcb, pmeta, centb, csp);
    fused_k<<<NB * 9, 256, 0, stream>>>(embb, centb, csp, pcb, pmeta, prev, chgflag, 1, (float*)d_out);
    reduce_k<<<NB * 3, 256, 0, stream>>>(pcb, pmeta, centb, csp);
    fused_k<<<NB * 9, 256, 0, stream>>>(embb, centb, csp, pcb, pmeta, prev, chgflag, 0, (float*)d_out);
    tail_k<<<NB, 576, 0, stream>>>(embb, pcb, pmeta, prev, chgflag, (float*)d_out);
}

// Round 13
// 151.583 us; speedup vs baseline: 1.2915x; 1.1169x over previous
//
#include <hip/hip_runtime.h>

#define NB 128
#define NP 576
#define NK 9
#define EMB 768
#define SGRID 24
#define COMPF 3.0f
#define NITER 10
#define EPSV 1e-8f

typedef short v8s __attribute__((ext_vector_type(8)));
typedef float v4f __attribute__((ext_vector_type(4)));

__device__ __forceinline__ unsigned short f2b(float f) {
    unsigned x = __float_as_uint(f);
    unsigned r = (x + 0x7fffu + ((x >> 16) & 1u)) >> 16;
    return (unsigned short)r;
}
__device__ __forceinline__ float b2f(unsigned short u) {
    return __uint_as_float(((unsigned)u) << 16);
}

// ---------------- init: fp32->bf16 conversion + indicator partials ----------
// 9 tiles of 64 points per item. Partials bf16, meta (sx,sy,w) fp32.
__global__ __launch_bounds__(192) void init_k(const float* __restrict__ emb,
                                              unsigned short* __restrict__ embb,
                                              unsigned short* __restrict__ pcb,
                                              float* __restrict__ pmeta,
                                              int* __restrict__ chgflag) {
    int blk = blockIdx.x, b = blk / 9, pb = blk % 9;
    int t = threadIdx.x;
    int ay = pb / 3;

    if (pb == 0 && t == 0) chgflag[b] = 0;

    float a0x=0,a0y=0,a0z=0,a0w=0, a1x=0,a1y=0,a1z=0,a1w=0, a2x=0,a2y=0,a2z=0,a2w=0;
    const float* eg = emb + ((size_t)b * NP + pb * 64) * EMB + t * 4;
    unsigned short* og = embb + ((size_t)b * NP + pb * 64) * EMB + t * 4;
    for (int p = 0; p < 64; ++p) {
        float4 f = *(const float4*)(eg + (size_t)p * EMB);
        ushort4 u;
        u.x = f2b(f.x); u.y = f2b(f.y); u.z = f2b(f.z); u.w = f2b(f.w);
        *(ushort4*)(og + (size_t)p * EMB) = u;
        int pg = pb * 64 + p;
        int sel = (pg % SGRID) >> 3;
        bool m0 = (sel == 0), m1 = (sel == 1), m2 = (sel == 2);
        a0x += m0 ? f.x : 0.f; a0y += m0 ? f.y : 0.f; a0z += m0 ? f.z : 0.f; a0w += m0 ? f.w : 0.f;
        a1x += m1 ? f.x : 0.f; a1y += m1 ? f.y : 0.f; a1z += m1 ? f.z : 0.f; a1w += m1 ? f.w : 0.f;
        a2x += m2 ? f.x : 0.f; a2y += m2 ? f.y : 0.f; a2z += m2 ? f.z : 0.f; a2w += m2 ? f.w : 0.f;
    }
    unsigned short* pc = pcb + (size_t)(b * 9 + pb) * NK * EMB;
    #pragma unroll
    for (int k = 0; k < NK; ++k) {
        int s = k - ay * 3;
        float vx = 0.f, vy = 0.f, vz = 0.f, vw = 0.f;
        if (s == 0) { vx = a0x; vy = a0y; vz = a0z; vw = a0w; }
        if (s == 1) { vx = a1x; vy = a1y; vz = a1z; vw = a1w; }
        if (s == 2) { vx = a2x; vy = a2y; vz = a2z; vw = a2w; }
        ushort4 u;
        u.x = f2b(vx); u.y = f2b(vy); u.z = f2b(vz); u.w = f2b(vw);
        *(ushort4*)&pc[k * EMB + t * 4] = u;
    }
    if (t < NK) {
        int s = t - ay * 3;
        float w = 0.f, sx = 0.f, sy = 0.f;
        if (s >= 0 && s < 3) {
            for (int p = 0; p < 64; ++p) {
                int pg = pb * 64 + p;
                if (((pg % SGRID) >> 3) == s) {
                    w += 1.f;
                    sx += (float)(pg % SGRID) * COMPF;
                    sy += (float)(pg / SGRID) * COMPF;
                }
            }
        }
        *(float4*)&pmeta[((size_t)(b * 9 + pb) * NK + t) * 4] =
            make_float4(sx, sy, w, 0.f);
    }
}

// ---------------- fused: reg-prefetched MFMA assign + WTA partial update ----
// grid NB*9, 256 thr (4 waves), 64-pt tiles. A-fragments loaded DIRECTLY from
// global into a depth-6 unrolled VGPR ring (12 loads / 12KB in flight per
// wave); no A-LDS, no barriers in the K-loop. B operand staged in LDS.
__global__ __launch_bounds__(256) void fused_k(
    const unsigned short* __restrict__ embb,
    const unsigned short* __restrict__ centb,
    const float* __restrict__ csp,
    unsigned short* __restrict__ pcb,          // [NB][9][NK][EMB] bf16
    float* __restrict__ pmeta,                 // [NB][9][NK][4] {sx,sy,w,_}
    unsigned char* __restrict__ prev,
    int* __restrict__ chgflag,
    int itFirst,              // 1: A_0 pass (no out); 0: compare + softmax out
    float* __restrict__ out)
{
    __shared__ unsigned short sc[16][776];     // B operand (+pad)
    __shared__ float scx[16], scy[16], sc2[16];
    __shared__ int swin[64];
    __shared__ int scnt[NK];
    __shared__ unsigned char splist[NK][64];
    __shared__ int tileChg;

    int blk = blockIdx.x;
    int b = blk / 9, pb = blk % 9;
    int t = threadIdx.x, lane = t & 63, wv = t >> 6;
    int r16 = lane & 15, g = lane >> 4;

    // stage centroids (B), zero-pad clusters 9..15
    const unsigned short* cg = centb + (size_t)b * NK * EMB;
    for (int i = t; i < NK * 96; i += 256) {
        int k = i / 96, s = i % 96;
        *(v8s*)&sc[k][s * 8] = *(const v8s*)&cg[k * EMB + s * 8];
    }
    for (int i = t; i < 7 * 96; i += 256) {
        int k = 9 + i / 96, s = i % 96;
        v8s z = {0,0,0,0,0,0,0,0};
        *(v8s*)&sc[k][s * 8] = z;
    }
    if (t < 16) {
        scx[t] = (t < NK) ? csp[((size_t)b * NK + t) * 2 + 0] : 0.f;
        scy[t] = (t < NK) ? csp[((size_t)b * NK + t) * 2 + 1] : 0.f;
    }
    if (t == 0) tileChg = itFirst;

    // per-lane A-fragment base: row = wv*16 + r16, slice g
    const unsigned short* eg = embb + ((size_t)b * NP + pb * 64) * EMB;
    const unsigned short* ap = eg + (size_t)(wv * 16 + r16) * EMB + g * 8;

    // prefetch chunks 0..5 into the register ring (before the barrier)
    v8s ra0[6], ra1[6];
    #pragma unroll
    for (int i = 0; i < 6; ++i) {
        ra0[i] = *(const v8s*)(ap + i * 64);
        ra1[i] = *(const v8s*)(ap + i * 64 + 32);
    }

    __syncthreads();   // sc/scx/scy staged

    // c2 from staged bf16 centroids — wave 0
    if (wv == 0) {
        for (int k = 0; k < NK; ++k) {
            float s = 0.f;
            const unsigned short* ck = sc[k];
            for (int c = lane; c < EMB; c += 64) { float v = b2f(ck[c]); s += v * v; }
            #pragma unroll
            for (int m = 1; m < 64; m <<= 1) s += __shfl_xor(s, m);
            if (lane == 0) sc2[k] = s + scx[k] * scx[k] + scy[k] * scy[k];
        }
        if (lane >= NK && lane < 16) sc2[lane] = 1e30f;
    }

    // K-loop: 12 chunks of 64ch; A from register ring, B from LDS
    v4f acc = {0.f, 0.f, 0.f, 0.f};
    const unsigned short* scrow = sc[r16];
    #pragma unroll
    for (int cn = 0; cn < 12; ++cn) {
        v8s a0 = ra0[cn % 6];
        v8s b0 = *(const v8s*)&scrow[cn * 64 + g * 8];
        acc = __builtin_amdgcn_mfma_f32_16x16x32_bf16(a0, b0, acc, 0, 0, 0);
        v8s a1 = ra1[cn % 6];
        v8s b1 = *(const v8s*)&scrow[cn * 64 + 32 + g * 8];
        acc = __builtin_amdgcn_mfma_f32_16x16x32_bf16(a1, b1, acc, 0, 0, 0);
        if (cn + 6 < 12) {
            ra0[cn % 6] = *(const v8s*)(ap + (cn + 6) * 64);
            ra1[cn % 6] = *(const v8s*)(ap + (cn + 6) * 64 + 32);
        }
    }

    __syncthreads();   // all waves' sc2 visible

    // epilogue: argmax always; softmax+out only on compare pass
    float cxv = scx[r16], cyv = scy[r16], c2v = sc2[r16];
    #pragma unroll
    for (int j = 0; j < 4; ++j) {
        int lr = wv * 16 + g * 4 + j;
        int p = pb * 64 + lr;
        float px = (float)(p % SGRID) * COMPF;
        float py = (float)(p / SGRID) * COMPF;
        float lg = 2.f * (acc[j] + px * cxv + py * cyv) - c2v;
        float mx = lg;
        mx = fmaxf(mx, __shfl_xor(mx, 1));
        mx = fmaxf(mx, __shfl_xor(mx, 2));
        mx = fmaxf(mx, __shfl_xor(mx, 4));
        mx = fmaxf(mx, __shfl_xor(mx, 8));
        if (!itFirst) {
            float e = __expf(lg - mx);
            float se = e;
            se += __shfl_xor(se, 1);
            se += __shfl_xor(se, 2);
            se += __shfl_xor(se, 4);
            se += __shfl_xor(se, 8);
            if (r16 < NK) out[((size_t)b * NP + p) * NK + r16] = e / se;
        }
        unsigned long long wm = __ballot(lg == mx);
        int ki = (int)(__ffsll((unsigned long long)((wm >> (lane & 48)) & 0xFFFFull)) - 1);
        if (r16 == 0) swin[lr] = ki;
    }
    __syncthreads();   // swin complete

    // convergence compare (wave 1) + per-cluster lists (all waves)
    if (wv == 1) {
        unsigned char* prevb = prev + (size_t)b * NP + pb * 64;
        unsigned char neww = (unsigned char)swin[lane];
        if (!itFirst) {
            bool diff = (prevb[lane] != neww);
            unsigned long long m = __ballot(diff);
            if (lane == 0 && m != 0ull) { chgflag[b] = 1; tileChg = 1; }
        }
        prevb[lane] = neww;
    }
    {
        int myk = swin[lane];
        for (int kk = wv; kk < NK; kk += 4) {
            unsigned long long msk = __ballot(myk == kk);
            int pos = __popcll(msk & ((1ull << lane) - 1ull));
            if (myk == kk) splist[kk][pos] = (unsigned char)lane;
            if (lane == 0) scnt[kk] = __popcll(msk);
        }
    }
    __syncthreads();   // lists + tileChg final

    // partial update: skipped when this tile's assignment is unchanged
    if (tileChg) {
        if (t < NK) {
            int n = scnt[t];
            float sx = 0.f, sy = 0.f;
            for (int i = 0; i < n; ++i) {
                int p = pb * 64 + splist[t][i];
                sx += (float)(p % SGRID);
                sy += (float)(p / SGRID);
            }
            *(float4*)&pmeta[((size_t)(b * 9 + pb) * NK + t) * 4] =
                make_float4(sx * COMPF, sy * COMPF, (float)n, 0.f);
        }
        if (t < 192) {
            unsigned short* pcw = pcb + (size_t)(b * 9 + pb) * NK * EMB;
            const unsigned short* e2 = eg + 4 * t;
            #pragma unroll
            for (int k = 0; k < NK; ++k) {
                int n = scnt[k];
                float a0 = 0.f, a1 = 0.f, a2 = 0.f, a3 = 0.f;
                for (int i = 0; i < n; ++i) {
                    int p = splist[k][i];
                    ushort4 u = *(const ushort4*)(e2 + (size_t)p * EMB);
                    a0 += b2f(u.x); a1 += b2f(u.y); a2 += b2f(u.z); a3 += b2f(u.w);
                }
                ushort4 o;
                o.x = f2b(a0); o.y = f2b(a1); o.z = f2b(a2); o.w = f2b(a3);
                *(ushort4*)&pcw[k * EMB + t * 4] = o;
            }
        }
    }
}

// ---------------- reduce: 9 bf16 partials -> bf16 centroids + csp -----------
__global__ __launch_bounds__(256) void reduce_k(const unsigned short* __restrict__ pcb,
                                                const float* __restrict__ pmeta,
                                                unsigned short* __restrict__ centb,
                                                float* __restrict__ csp) {
    __shared__ float sw[NK];
    int b = blockIdx.x / 3, cb = blockIdx.x % 3;
    int t = threadIdx.x;
    const unsigned short* pc = pcb + (size_t)b * 9 * NK * EMB;
    const float* pm = pmeta + (size_t)b * 9 * NK * 4;

    if (t < NK) {
        float w = 0.f, sx = 0.f, sy = 0.f;
        for (int s = 0; s < 9; ++s) {
            const float* q = pm + (size_t)(s * NK + t) * 4;
            sx += q[0]; sy += q[1]; w += q[2];
        }
        float wi = w + EPSV;
        sw[t] = wi;
        if (cb == 0) {
            csp[((size_t)b * NK + t) * 2 + 0] = sx / wi;
            csp[((size_t)b * NK + t) * 2 + 1] = sy / wi;
        }
    }
    __syncthreads();

    int c = cb * 256 + t;
    #pragma unroll
    for (int k = 0; k < NK; ++k) {
        float v = 0.f;
        #pragma unroll
        for (int s = 0; s < 9; ++s) v += b2f(pc[(size_t)(s * NK + k) * EMB + c]);
        centb[((size_t)b * NK + k) * EMB + c] = f2b(v / sw[k]);
    }
}

// ---------------- tail: persistent per-item finisher (stub when converged) --
__global__ __launch_bounds__(576) void tail_k(
    const unsigned short* __restrict__ embb,
    const unsigned short* __restrict__ pcb,
    const float* __restrict__ pmeta,
    const unsigned char* __restrict__ prevg,
    const int* __restrict__ chgflag,
    float* __restrict__ out)
{
    __shared__ unsigned short sc[16][776];
    __shared__ unsigned short sa[3][2][48][64];
    __shared__ float cacc[NK][EMB];
    __shared__ float cw[NK], csx[NK], csy[NK];
    __shared__ float scx[16], scy[16], sc2[16];
    __shared__ unsigned char prev[NP];
    __shared__ unsigned char swin[3][48];
    __shared__ unsigned char splist[3][NK][48];
    __shared__ int scnt[3][NK];
    __shared__ int chg;

    int b = blockIdx.x;
    if (chgflag[b] == 0) return;

    int t = threadIdx.x, lane = t & 63, wv = t >> 6;
    int grp = wv / 3, wg = wv % 3, gt = t - grp * 192;
    int r16 = lane & 15, g = lane >> 4;
    const unsigned short* ib = embb + (size_t)b * NP * EMB;

    typedef short v8s2 __attribute__((ext_vector_type(8)));
    for (int i = t; i < 7 * 96; i += 576) {
        int k = 9 + i / 96, s = i % 96;
        v8s2 z = {0,0,0,0,0,0,0,0};
        *(v8s2*)&sc[k][s * 8] = z;
    }
    if (t >= NK && t < 16) { scx[t] = 0.f; scy[t] = 0.f; sc2[t] = 1e30f; }
    for (int i = t; i < NP; i += 576) prev[i] = prevg[(size_t)b * NP + i];

    const unsigned short* pcb16 = pcb + (size_t)b * 9 * NK * EMB;
    const float* pmb = pmeta + (size_t)b * 9 * NK * 4;
    if (t < 192) {
        int ch = t * 4;
        #pragma unroll
        for (int k = 0; k < NK; ++k) {
            float s0 = 0.f, s1 = 0.f, s2 = 0.f, s3 = 0.f;
            #pragma unroll
            for (int s9 = 0; s9 < 9; ++s9) {
                ushort4 q = *(const ushort4*)&pcb16[(size_t)(s9 * NK + k) * EMB + ch];
                s0 += b2f(q.x); s1 += b2f(q.y); s2 += b2f(q.z); s3 += b2f(q.w);
            }
            cacc[k][ch] = s0; cacc[k][ch+1] = s1; cacc[k][ch+2] = s2; cacc[k][ch+3] = s3;
        }
    }
    if (t < NK) {
        float w = 0.f, sx = 0.f, sy = 0.f;
        for (int s9 = 0; s9 < 9; ++s9) {
            const float* q = pmb + (size_t)(s9 * NK + t) * 4;
            sx += q[0]; sy += q[1]; w += q[2];
        }
        cw[t] = w; csx[t] = sx; csy[t] = sy;
    }
    __syncthreads();

    for (int it = 2; it <= NITER; ++it) {
        bool lastPass = (it == NITER);

        if (t < 192) {
            int ch = t * 4;
            #pragma unroll
            for (int k = 0; k < NK; ++k) {
                float inv = 1.f / (cw[k] + EPSV);
                ushort4 u;
                u.x = f2b(cacc[k][ch] * inv);
                u.y = f2b(cacc[k][ch+1] * inv);
                u.z = f2b(cacc[k][ch+2] * inv);
                u.w = f2b(cacc[k][ch+3] * inv);
                *(ushort4*)&sc[k][ch] = u;
            }
        }
        if (t < NK) {
            float inv = 1.f / (cw[t] + EPSV);
            scx[t] = csx[t] * inv;
            scy[t] = csy[t] * inv;
        }
        __syncthreads();

        if (wv < NK) {
            float s = 0.f;
            const unsigned short* ck = sc[wv];
            #pragma unroll
            for (int c = 0; c < EMB / 64; ++c) {
                float v = b2f(ck[lane + c * 64]); s += v * v;
            }
            #pragma unroll
            for (int m = 1; m < 64; m <<= 1) s += __shfl_xor(s, m);
            if (lane == 0) sc2[wv] = s + scx[wv] * scx[wv] + scy[wv] * scy[wv];
        }
        for (int i = t; i < NK * EMB; i += 576) ((float*)cacc)[i] = 0.f;
        if (t < NK) { cw[t] = 0.f; csx[t] = 0.f; csy[t] = 0.f; }
        if (t == 0) chg = 0;
        __syncthreads();

        float acc2[NK][4];
        #pragma unroll
        for (int k = 0; k < NK; ++k) { acc2[k][0]=0.f; acc2[k][1]=0.f; acc2[k][2]=0.f; acc2[k][3]=0.f; }
        float wreg = 0.f, sxreg = 0.f, syreg = 0.f;

        for (int rd = 0; rd < 4; ++rd) {
            int tileBase = (rd * 3 + grp) * 48;
            int sr = gt >> 3, sl = gt & 7;
            int sphys = (sl ^ (sr & 7)) * 8;
            const unsigned short* gb = ib + (size_t)(tileBase + sr) * EMB + sl * 8;
            v8s s0 = *(const v8s*)(gb);
            v8s s1 = *(const v8s*)(gb + 24 * EMB);
            *(v8s*)&sa[grp][0][sr][sphys] = s0;
            *(v8s*)&sa[grp][0][sr + 24][sphys] = s1;

            v4f acc = {0.f, 0.f, 0.f, 0.f};
            int lrow = wg * 16 + r16;
            for (int cn = 0; cn < 12; ++cn) {
                v8s n0, n1;
                if (cn < 11) {
                    n0 = *(const v8s*)(gb + (cn + 1) * 64);
                    n1 = *(const v8s*)(gb + (cn + 1) * 64 + 24 * EMB);
                }
                __syncthreads();
                int cur = cn & 1;
                #pragma unroll
                for (int ks = 0; ks < 2; ++ks) {
                    v8s af = *(const v8s*)&sa[grp][cur][lrow][(((ks << 2) + g) ^ (r16 & 7)) << 3];
                    v8s bf = *(const v8s*)&sc[r16][cn * 64 + ks * 32 + g * 8];
                    acc = __builtin_amdgcn_mfma_f32_16x16x32_bf16(af, bf, acc, 0, 0, 0);
                }
                if (cn < 11) {
                    *(v8s*)&sa[grp][cur ^ 1][sr][sphys] = n0;
                    *(v8s*)&sa[grp][cur ^ 1][sr + 24][sphys] = n1;
                }
            }

            float cxv = scx[r16], cyv = scy[r16], c2v = sc2[r16];
            #pragma unroll
            for (int j = 0; j < 4; ++j) {
                int lr = wg * 16 + g * 4 + j;
                int p = tileBase + lr;
                float px = (float)(p % SGRID) * COMPF;
                float py = (float)(p / SGRID) * COMPF;
                float lg = 2.f * (acc[j] + px * cxv + py * cyv) - c2v;
                float mx = lg;
                mx = fmaxf(mx, __shfl_xor(mx, 1));
                mx = fmaxf(mx, __shfl_xor(mx, 2));
                mx = fmaxf(mx, __shfl_xor(mx, 4));
                mx = fmaxf(mx, __shfl_xor(mx, 8));
                float e = __expf(lg - mx);
                float se = e;
                se += __shfl_xor(se, 1);
                se += __shfl_xor(se, 2);
                se += __shfl_xor(se, 4);
                se += __shfl_xor(se, 8);
                if (r16 < NK) out[((size_t)b * NP + p) * NK + r16] = e / se;
                if (!lastPass) {
                    float m = lg; int ki = r16;
                    #pragma unroll
                    for (int d = 1; d < 16; d <<= 1) {
                        float om = __shfl_xor(m, d);
                        int oi = __shfl_xor(ki, d);
                        if (om > m || (om == m && oi < ki)) { m = om; ki = oi; }
                    }
                    if (r16 == 0) swin[grp][lr] = (unsigned char)ki;
                }
            }

            if (!lastPass) {
                __syncthreads();
                if (wg == 0) {
                    unsigned char myk = swin[grp][lane < 48 ? lane : 0];
                    bool diff = false;
                    if (lane < 48) {
                        int p = tileBase + lane;
                        diff = (prev[p] != myk);
                        prev[p] = myk;
                    }
                    unsigned long long dm = __ballot(diff);
                    if (lane == 0 && dm != 0ull) chg = 1;
                    unsigned long long lmask = (1ull << lane) - 1ull;
                    #pragma unroll
                    for (int kk = 0; kk < NK; ++kk) {
                        unsigned long long msk = __ballot(lane < 48 && myk == (unsigned char)kk);
                        int pos = __popcll(msk & lmask);
                        if (lane < 48 && myk == (unsigned char)kk)
                            splist[grp][kk][pos] = (unsigned char)lane;
                        if (lane == 0) scnt[grp][kk] = __popcll(msk);
                    }
                }
                __syncthreads();

                if (wg == 0 && lane < NK) {
                    int n = scnt[grp][lane];
                    float sx = 0.f, sy = 0.f;
                    for (int i = 0; i < n; ++i) {
                        int p = tileBase + splist[grp][lane][i];
                        sx += (float)(p % SGRID);
                        sy += (float)(p / SGRID);
                    }
                    wreg += (float)n; sxreg += sx; syreg += sy;
                }
                const unsigned short* e2 = ib + (size_t)tileBase * EMB + gt * 4;
                #pragma unroll
                for (int k = 0; k < NK; ++k) {
                    int n = scnt[grp][k];
                    float a0 = acc2[k][0], a1 = acc2[k][1], a2 = acc2[k][2], a3 = acc2[k][3];
                    for (int i = 0; i < n; ++i) {
                        int row = splist[grp][k][i];
                        ushort4 u = *(const ushort4*)(e2 + (size_t)row * EMB);
                        a0 += b2f(u.x); a1 += b2f(u.y); a2 += b2f(u.z); a3 += b2f(u.w);
                    }
                    acc2[k][0] = a0; acc2[k][1] = a1; acc2[k][2] = a2; acc2[k][3] = a3;
                }
            }
        }

        if (lastPass) break;
        if (chg == 0) break;

        for (int g3 = 0; g3 < 3; ++g3) {
            if (grp == g3) {
                int ch = gt * 4;
                #pragma unroll
                for (int k = 0; k < NK; ++k) {
                    cacc[k][ch]   += acc2[k][0];
                    cacc[k][ch+1] += acc2[k][1];
                    cacc[k][ch+2] += acc2[k][2];
                    cacc[k][ch+3] += acc2[k][3];
                }
                if (wg == 0 && lane < NK) {
                    cw[lane]  += wreg;
                    csx[lane] += sxreg * COMPF;
                    csy[lane] += syreg * COMPF;
                }
            }
            __syncthreads();
        }
    }
}

extern "C" void kernel_launch(void* const* d_in, const int* in_sizes, int n_in,
                              void* d_out, int out_size, void* d_ws, size_t ws_size,
                              hipStream_t stream) {
    const float* emb = (const float*)d_in[0];
    char* w = (char*)d_ws;
    unsigned short* embb = (unsigned short*)w;  w += (size_t)NB * NP * EMB * 2;      // 113.2 MB
    unsigned short* pcb = (unsigned short*)w;   w += (size_t)NB * 9 * NK * EMB * 2;  // 15.9 MB
    float* pmeta = (float*)w;                   w += (size_t)NB * 9 * NK * 4 * 4;    // 0.66 MB
    unsigned short* centb = (unsigned short*)w; w += (size_t)NB * NK * EMB * 2;      // 1.8 MB
    float* csp = (float*)w;                     w += (size_t)NB * NK * 2 * 4;
    unsigned char* prev = (unsigned char*)w;    w += (size_t)NB * NP;
    int* chgflag = (int*)w;                     w += (size_t)NB * 4;

    init_k<<<NB * 9, 192, 0, stream>>>(emb, embb, pcb, pmeta, chgflag);
    reduce_k<<<NB * 3, 256, 0, stream>>>(pcb, pmeta, centb, csp);
    fused_k<<<NB * 9, 256, 0, stream>>>(embb, centb, csp, pcb, pmeta, prev, chgflag, 1, (float*)d_out);
    reduce_k<<<NB * 3, 256, 0, stream>>>(pcb, pmeta, centb, csp);
    fused_k<<<NB * 9, 256, 0, stream>>>(embb, centb, csp, pcb, pmeta, prev, chgflag, 0, (float*)d_out);
    tail_k<<<NB, 576, 0, stream>>>(embb, pcb, pmeta, prev, chgflag, (float*)d_out);
}